// Round 1
// baseline (1261.108 us; speedup 1.0000x reference)
//
#include <hip/hip_runtime.h>
#include <math.h>

#define BATCH 64
#define SEQ   4096
#define DIM   1024

// Pass 1: per-(batch, split) online-softmax partial.
// Block = 256 threads = 4 waves. Each wave independently processes rows
// s0+wave, s0+wave+4, ... of its chunk. A wave's 64 lanes hold the full
// D=1024 row: lane owns cols {q*256 + lane*4 + j}, q=0..3, j=0..3.
__global__ __launch_bounds__(256)
void attn_partial_kernel(const float* __restrict__ inp,
                         const int*   __restrict__ lens,
                         const float* __restrict__ w,
                         float* __restrict__ ws_c,
                         float* __restrict__ ws_m,
                         float* __restrict__ ws_l,
                         int splits, int chunk)
{
    const int split = blockIdx.x;
    const int b     = blockIdx.y;
    const int t     = threadIdx.x;
    const int wave  = t >> 6;
    const int lane  = t & 63;
    const int colb  = lane * 4;

    __shared__ float c_s[4][DIM];
    __shared__ float m_s[4];
    __shared__ float l_s[4];

    const int len = lens[b];
    const int s0  = split * chunk;
    const int s1  = min(s0 + chunk, len);   // rows >= len are masked: skip entirely

    // weight fragment (reused every row)
    const float4 w0 = *(const float4*)(w       + colb);
    const float4 w1 = *(const float4*)(w + 256 + colb);
    const float4 w2 = *(const float4*)(w + 512 + colb);
    const float4 w3 = *(const float4*)(w + 768 + colb);

    float  m  = -INFINITY, l = 0.0f;
    float4 c0 = {0,0,0,0}, c1 = {0,0,0,0}, c2 = {0,0,0,0}, c3 = {0,0,0,0};

    const float* base = inp + (size_t)b * SEQ * DIM + colb;

    for (int s = s0 + wave; s < s1; s += 4) {
        const float* rp = base + (size_t)s * DIM;
        const float4 x0 = *(const float4*)(rp);
        const float4 x1 = *(const float4*)(rp + 256);
        const float4 x2 = *(const float4*)(rp + 512);
        const float4 x3 = *(const float4*)(rp + 768);

        float pd = x0.x*w0.x + x0.y*w0.y + x0.z*w0.z + x0.w*w0.w
                 + x1.x*w1.x + x1.y*w1.y + x1.z*w1.z + x1.w*w1.w
                 + x2.x*w2.x + x2.y*w2.y + x2.z*w2.z + x2.w*w2.w
                 + x3.x*w3.x + x3.y*w3.y + x3.z*w3.z + x3.w*w3.w;

        // wave-wide butterfly sum (all 64 lanes end with the row score)
        #pragma unroll
        for (int off = 32; off > 0; off >>= 1)
            pd += __shfl_xor(pd, off, 64);
        // bias b[0] omitted: softmax is shift-invariant.

        const float mn    = fmaxf(m, pd);
        const float alpha = __expf(m - mn);   // m=-inf first iter -> alpha=0 (mn finite)
        const float p     = __expf(pd - mn);
        l = l * alpha + p;
        c0.x = c0.x*alpha + p*x0.x;  c0.y = c0.y*alpha + p*x0.y;
        c0.z = c0.z*alpha + p*x0.z;  c0.w = c0.w*alpha + p*x0.w;
        c1.x = c1.x*alpha + p*x1.x;  c1.y = c1.y*alpha + p*x1.y;
        c1.z = c1.z*alpha + p*x1.z;  c1.w = c1.w*alpha + p*x1.w;
        c2.x = c2.x*alpha + p*x2.x;  c2.y = c2.y*alpha + p*x2.y;
        c2.z = c2.z*alpha + p*x2.z;  c2.w = c2.w*alpha + p*x2.w;
        c3.x = c3.x*alpha + p*x3.x;  c3.y = c3.y*alpha + p*x3.y;
        c3.z = c3.z*alpha + p*x3.z;  c3.w = c3.w*alpha + p*x3.w;
        m = mn;
    }

    // merge the 4 waves' partials through LDS
    *(float4*)&c_s[wave][colb      ] = c0;
    *(float4*)&c_s[wave][colb + 256] = c1;
    *(float4*)&c_s[wave][colb + 512] = c2;
    *(float4*)&c_s[wave][colb + 768] = c3;
    if (lane == 0) { m_s[wave] = m; l_s[wave] = l; }
    __syncthreads();

    const float M = fmaxf(fmaxf(m_s[0], m_s[1]), fmaxf(m_s[2], m_s[3]));
    float sc[4];
    float L = 0.0f;
    #pragma unroll
    for (int iw = 0; iw < 4; ++iw) {
        // guard: all-empty block has every m_s=-inf; -inf - -inf = NaN
        sc[iw] = (m_s[iw] == -INFINITY) ? 0.0f : __expf(m_s[iw] - M);
        L += sc[iw] * l_s[iw];
    }

    const int oc = t * 4;
    float4 acc = {0,0,0,0};
    #pragma unroll
    for (int iw = 0; iw < 4; ++iw) {
        const float4 ci = *(const float4*)&c_s[iw][oc];
        acc.x += sc[iw]*ci.x; acc.y += sc[iw]*ci.y;
        acc.z += sc[iw]*ci.z; acc.w += sc[iw]*ci.w;
    }

    const size_t idx = (size_t)b * splits + split;
    *(float4*)(ws_c + idx * DIM + oc) = acc;
    if (t == 0) { ws_m[idx] = M; ws_l[idx] = L; }
}

// Pass 2: combine the per-split partials for each batch.
__global__ __launch_bounds__(256)
void attn_reduce_kernel(const float* __restrict__ ws_c,
                        const float* __restrict__ ws_m,
                        const float* __restrict__ ws_l,
                        float* __restrict__ out, int splits)
{
    const int b  = blockIdx.x;
    const int t  = threadIdx.x;
    const int oc = t * 4;

    const float* mb = ws_m + (size_t)b * splits;
    const float* lb = ws_l + (size_t)b * splits;

    float M = -INFINITY;
    for (int i = 0; i < splits; ++i) M = fmaxf(M, mb[i]);
    // len >= 1 guarantees split 0 is non-empty -> M finite.

    float  L   = 0.0f;
    float4 acc = {0,0,0,0};
    for (int i = 0; i < splits; ++i) {
        const float mi  = mb[i];
        const float scl = (mi == -INFINITY) ? 0.0f : __expf(mi - M);
        L += scl * lb[i];
        const float4 ci = *(const float4*)(ws_c + ((size_t)b * splits + i) * DIM + oc);
        acc.x += scl*ci.x; acc.y += scl*ci.y;
        acc.z += scl*ci.z; acc.w += scl*ci.w;
    }
    const float inv = 1.0f / L;
    float4 o = { acc.x*inv, acc.y*inv, acc.z*inv, acc.w*inv };
    *(float4*)(out + (size_t)b * DIM + oc) = o;
}

extern "C" void kernel_launch(void* const* d_in, const int* in_sizes, int n_in,
                              void* d_out, int out_size, void* d_ws, size_t ws_size,
                              hipStream_t stream) {
    const float* inp  = (const float*)d_in[0];
    const int*   lens = (const int*)  d_in[1];
    const float* w    = (const float*)d_in[2];
    // d_in[3] (bias) intentionally unused: softmax(x + c) == softmax(x).
    float* out = (float*)d_out;

    int splits = 32;
    while (splits > 1 &&
           (size_t)BATCH * splits * (DIM + 2) * sizeof(float) > ws_size)
        splits >>= 1;
    const int chunk = SEQ / splits;

    float* wsf  = (float*)d_ws;
    float* ws_c = wsf;                                   // [B*splits, DIM]
    float* ws_m = wsf + (size_t)BATCH * splits * DIM;    // [B*splits]
    float* ws_l = ws_m + (size_t)BATCH * splits;         // [B*splits]

    attn_partial_kernel<<<dim3(splits, BATCH), 256, 0, stream>>>(
        inp, lens, w, ws_c, ws_m, ws_l, splits, chunk);
    attn_reduce_kernel<<<BATCH, 256, 0, stream>>>(ws_c, ws_m, ws_l, out, splits);
}

// Round 2
// 1245.748 us; speedup vs baseline: 1.0123x; 1.0123x over previous
//
#include <hip/hip_runtime.h>
#include <math.h>

#define BATCH 64
#define SEQ   4096
#define DIM   1024

// Pass 1: per-(batch, split) online-softmax partial, 4 rows per iteration.
// Block = 256 threads = 4 waves; each wave owns a contiguous sub-range of the
// block's row chunk. A wave's 64 lanes hold a full D=1024 row: lane owns cols
// {q*256 + lane*4 + j}, q=0..3, j=0..3.
__global__ __launch_bounds__(256, 4)
void attn_partial_kernel(const float* __restrict__ inp,
                         const int*   __restrict__ lens,
                         const float* __restrict__ w,
                         float* __restrict__ ws_c,
                         float* __restrict__ ws_m,
                         float* __restrict__ ws_l,
                         int splits)
{
    const int split = blockIdx.x;
    const int b     = blockIdx.y;
    const int t     = threadIdx.x;
    const int wave  = t >> 6;
    const int lane  = t & 63;
    const int colb  = lane * 4;

    __shared__ float c_s[4][DIM];
    __shared__ float m_s[4];
    __shared__ float l_s[4];

    const int len   = lens[b];
    // per-batch balanced chunking: every block gets <= ceil(len/splits) rows
    const int chunk = (len + splits - 1) / splits;
    const int s0    = split * chunk;
    const int s1    = min(s0 + chunk, len);
    // contiguous per-wave sub-range
    const int n     = max(s1 - s0, 0);
    const int per   = (n + 3) >> 2;
    const int ws0   = s0 + wave * per;
    const int ws1   = min(ws0 + per, s1);

    // weight fragment (reused every row)
    const float4 w0 = *(const float4*)(w       + colb);
    const float4 w1 = *(const float4*)(w + 256 + colb);
    const float4 w2 = *(const float4*)(w + 512 + colb);
    const float4 w3 = *(const float4*)(w + 768 + colb);

    float  m = -INFINITY, l = 0.0f;
    float4 c0 = {0,0,0,0}, c1 = {0,0,0,0}, c2 = {0,0,0,0}, c3 = {0,0,0,0};

    const float* base = inp + (size_t)b * SEQ * DIM + colb;

    int s = ws0;
    // main loop: 4 rows per iteration (16 loads in flight, batched shuffles,
    // one rescale per group)
    for (; s + 4 <= ws1; s += 4) {
        const float* rp = base + (size_t)s * DIM;
        float4 x[4][4];
        #pragma unroll
        for (int j = 0; j < 4; ++j)
            #pragma unroll
            for (int q = 0; q < 4; ++q)
                x[j][q] = *(const float4*)(rp + j * DIM + q * 256);

        float pd[4];
        #pragma unroll
        for (int j = 0; j < 4; ++j) {
            const float4 a0 = x[j][0], a1 = x[j][1], a2 = x[j][2], a3 = x[j][3];
            pd[j] = a0.x*w0.x + a0.y*w0.y + a0.z*w0.z + a0.w*w0.w
                  + a1.x*w1.x + a1.y*w1.y + a1.z*w1.z + a1.w*w1.w
                  + a2.x*w2.x + a2.y*w2.y + a2.z*w2.z + a2.w*w2.w
                  + a3.x*w3.x + a3.y*w3.y + a3.z*w3.z + a3.w*w3.w;
        }

        // 4 independent 64-lane butterflies — latencies overlap
        #pragma unroll
        for (int off = 32; off > 0; off >>= 1) {
            #pragma unroll
            for (int j = 0; j < 4; ++j)
                pd[j] += __shfl_xor(pd[j], off, 64);
        }

        const float mn = fmaxf(m, fmaxf(fmaxf(pd[0], pd[1]), fmaxf(pd[2], pd[3])));
        const float alpha = __expf(m - mn);   // m=-inf first group -> alpha=0, mn finite
        float p[4];
        #pragma unroll
        for (int j = 0; j < 4; ++j) p[j] = __expf(pd[j] - mn);
        l = l * alpha + p[0] + p[1] + p[2] + p[3];

        #pragma unroll
        for (int q = 0; q < 4; ++q) {
            float4* cq = (q == 0) ? &c0 : (q == 1) ? &c1 : (q == 2) ? &c2 : &c3;
            cq->x = cq->x*alpha + p[0]*x[0][q].x + p[1]*x[1][q].x + p[2]*x[2][q].x + p[3]*x[3][q].x;
            cq->y = cq->y*alpha + p[0]*x[0][q].y + p[1]*x[1][q].y + p[2]*x[2][q].y + p[3]*x[3][q].y;
            cq->z = cq->z*alpha + p[0]*x[0][q].z + p[1]*x[1][q].z + p[2]*x[2][q].z + p[3]*x[3][q].z;
            cq->w = cq->w*alpha + p[0]*x[0][q].w + p[1]*x[1][q].w + p[2]*x[2][q].w + p[3]*x[3][q].w;
        }
        m = mn;
    }

    // tail rows (<=3)
    for (; s < ws1; ++s) {
        const float* rp = base + (size_t)s * DIM;
        const float4 x0 = *(const float4*)(rp);
        const float4 x1 = *(const float4*)(rp + 256);
        const float4 x2 = *(const float4*)(rp + 512);
        const float4 x3 = *(const float4*)(rp + 768);

        float pd = x0.x*w0.x + x0.y*w0.y + x0.z*w0.z + x0.w*w0.w
                 + x1.x*w1.x + x1.y*w1.y + x1.z*w1.z + x1.w*w1.w
                 + x2.x*w2.x + x2.y*w2.y + x2.z*w2.z + x2.w*w2.w
                 + x3.x*w3.x + x3.y*w3.y + x3.z*w3.z + x3.w*w3.w;
        #pragma unroll
        for (int off = 32; off > 0; off >>= 1)
            pd += __shfl_xor(pd, off, 64);

        const float mn    = fmaxf(m, pd);
        const float alpha = __expf(m - mn);
        const float p     = __expf(pd - mn);
        l = l * alpha + p;
        c0.x = c0.x*alpha + p*x0.x;  c0.y = c0.y*alpha + p*x0.y;
        c0.z = c0.z*alpha + p*x0.z;  c0.w = c0.w*alpha + p*x0.w;
        c1.x = c1.x*alpha + p*x1.x;  c1.y = c1.y*alpha + p*x1.y;
        c1.z = c1.z*alpha + p*x1.z;  c1.w = c1.w*alpha + p*x1.w;
        c2.x = c2.x*alpha + p*x2.x;  c2.y = c2.y*alpha + p*x2.y;
        c2.z = c2.z*alpha + p*x2.z;  c2.w = c2.w*alpha + p*x2.w;
        c3.x = c3.x*alpha + p*x3.x;  c3.y = c3.y*alpha + p*x3.y;
        c3.z = c3.z*alpha + p*x3.z;  c3.w = c3.w*alpha + p*x3.w;
        m = mn;
    }

    // merge the 4 waves' partials through LDS
    *(float4*)&c_s[wave][colb      ] = c0;
    *(float4*)&c_s[wave][colb + 256] = c1;
    *(float4*)&c_s[wave][colb + 512] = c2;
    *(float4*)&c_s[wave][colb + 768] = c3;
    if (lane == 0) { m_s[wave] = m; l_s[wave] = l; }
    __syncthreads();

    const float M = fmaxf(fmaxf(m_s[0], m_s[1]), fmaxf(m_s[2], m_s[3]));
    float sc[4];
    float L = 0.0f;
    #pragma unroll
    for (int iw = 0; iw < 4; ++iw) {
        // all-empty block: every m_s=-inf; guard the NaN from (-inf - -inf)
        sc[iw] = (m_s[iw] == -INFINITY) ? 0.0f : __expf(m_s[iw] - M);
        L += sc[iw] * l_s[iw];
    }

    const int oc = t * 4;
    float4 acc = {0,0,0,0};
    #pragma unroll
    for (int iw = 0; iw < 4; ++iw) {
        const float4 ci = *(const float4*)&c_s[iw][oc];
        acc.x += sc[iw]*ci.x; acc.y += sc[iw]*ci.y;
        acc.z += sc[iw]*ci.z; acc.w += sc[iw]*ci.w;
    }

    const size_t idx = (size_t)b * splits + split;
    *(float4*)(ws_c + idx * DIM + oc) = acc;
    if (t == 0) { ws_m[idx] = M; ws_l[idx] = L; }
}

// Pass 2: combine the per-split partials for each batch.
__global__ __launch_bounds__(256)
void attn_reduce_kernel(const float* __restrict__ ws_c,
                        const float* __restrict__ ws_m,
                        const float* __restrict__ ws_l,
                        float* __restrict__ out, int splits)
{
    const int b  = blockIdx.x;
    const int t  = threadIdx.x;
    const int oc = t * 4;

    const float* mb = ws_m + (size_t)b * splits;
    const float* lb = ws_l + (size_t)b * splits;

    float M = -INFINITY;
    #pragma unroll 8
    for (int i = 0; i < splits; ++i) M = fmaxf(M, mb[i]);
    // len >= 1 guarantees split 0 is non-empty -> M finite.

    float  L   = 0.0f;
    float4 acc = {0,0,0,0};
    #pragma unroll 4
    for (int i = 0; i < splits; ++i) {
        const float mi  = mb[i];
        const float scl = (mi == -INFINITY) ? 0.0f : __expf(mi - M);
        L += scl * lb[i];
        const float4 ci = *(const float4*)(ws_c + ((size_t)b * splits + i) * DIM + oc);
        acc.x += scl*ci.x; acc.y += scl*ci.y;
        acc.z += scl*ci.z; acc.w += scl*ci.w;
    }
    const float inv = 1.0f / L;
    float4 o = { acc.x*inv, acc.y*inv, acc.z*inv, acc.w*inv };
    *(float4*)(out + (size_t)b * DIM + oc) = o;
}

extern "C" void kernel_launch(void* const* d_in, const int* in_sizes, int n_in,
                              void* d_out, int out_size, void* d_ws, size_t ws_size,
                              hipStream_t stream) {
    const float* inp  = (const float*)d_in[0];
    const int*   lens = (const int*)  d_in[1];
    const float* w    = (const float*)d_in[2];
    // d_in[3] (bias) intentionally unused: softmax(x + c) == softmax(x).
    float* out = (float*)d_out;

    int splits = 32;
    while (splits > 1 &&
           (size_t)BATCH * splits * (DIM + 2) * sizeof(float) > ws_size)
        splits >>= 1;

    float* wsf  = (float*)d_ws;
    float* ws_c = wsf;                                   // [B*splits, DIM]
    float* ws_m = wsf + (size_t)BATCH * splits * DIM;    // [B*splits]
    float* ws_l = ws_m + (size_t)BATCH * splits;         // [B*splits]

    attn_partial_kernel<<<dim3(splits, BATCH), 256, 0, stream>>>(
        inp, lens, w, ws_c, ws_m, ws_l, splits);
    attn_reduce_kernel<<<BATCH, 256, 0, stream>>>(ws_c, ws_m, ws_l, out, splits);
}